// Round 1
// baseline (233.741 us; speedup 1.0000x reference)
//
#include <hip/hip_runtime.h>

typedef unsigned short u16;
typedef __attribute__((ext_vector_type(4))) unsigned short u16x4;
typedef __attribute__((ext_vector_type(8))) short short8;
typedef __attribute__((ext_vector_type(4))) float floatx4;

#define NB 8192        // rows
#define DK 1024        // D_IN
#define DN 1024        // D_OUT
#define NE 16          // experts
#define TM 128
#define TN 128
#define BK 64
#define MAX_TILES 80   // sum ceil(cnt_e/128) <= 64 + 16

__device__ __forceinline__ u16 f2bf(float f) {
    union { float f; unsigned int u; } v; v.f = f;
    unsigned int u = v.u;
    return (u16)((u + 0x7fffu + ((u >> 16) & 1u)) >> 16);
}

__device__ __forceinline__ void gld16(const void* g, void* l) {
    __builtin_amdgcn_global_load_lds(
        (const __attribute__((address_space(1))) unsigned int*)g,
        (__attribute__((address_space(3))) unsigned int*)l, 16, 0, 0);
}

// ---------------- K0: zero expert counters ----------------
__global__ void k_init(int* cnt) {
    if (threadIdx.x < NE) cnt[threadIdx.x] = 0;
}

// ---------------- K1: gate (fp64) + argmax + bucket + x->bf16 ----------------
// block = 256 threads, 16 rows per block. lane-(row,e) layout.
__global__ __launch_bounds__(256) void k_gate(const float* __restrict__ x,
                                              const float* __restrict__ Wg,
                                              const float* __restrict__ bg,
                                              u16* __restrict__ xb,
                                              int* __restrict__ cnt,
                                              int* __restrict__ bucket) {
    __shared__ float xs[16 * 132];    // [row][i] pad 132
    __shared__ float wgs[16 * 132];   // [e][i]  pad 132 (transposed Wg chunk)
    const int tid = threadIdx.x;
    const int R0 = blockIdx.x * 16;
    const int row_l = tid >> 4;
    const int e = tid & 15;

    double a0 = (double)bg[e], a1 = 0.0, a2 = 0.0, a3 = 0.0;

    for (int ci = 0; ci < 8; ++ci) {
        const int i0 = ci * 128;
        // stage x chunk [16][128] + write bf16 copy
        #pragma unroll
        for (int h = 0; h < 2; ++h) {
            int f = h * 256 + tid;
            int r = f >> 5;
            int i4 = (f & 31) * 4;
            float4 v = *(const float4*)&x[(size_t)(R0 + r) * DK + i0 + i4];
            *(float4*)&xs[r * 132 + i4] = v;
            u16x4 b; b.x = f2bf(v.x); b.y = f2bf(v.y); b.z = f2bf(v.z); b.w = f2bf(v.w);
            *(u16x4*)&xb[(size_t)(R0 + r) * DK + i0 + i4] = b;
        }
        // stage Wg chunk transposed: wgs[e][i]
        #pragma unroll
        for (int h = 0; h < 2; ++h) {
            int g = h * 256 + tid;
            int i = g >> 2;
            int e4 = (g & 3) * 4;
            float4 v = *(const float4*)&Wg[(size_t)(i0 + i) * NE + e4];
            wgs[(e4 + 0) * 132 + i] = v.x;
            wgs[(e4 + 1) * 132 + i] = v.y;
            wgs[(e4 + 2) * 132 + i] = v.z;
            wgs[(e4 + 3) * 132 + i] = v.w;
        }
        __syncthreads();
        #pragma unroll 8
        for (int i4 = 0; i4 < 32; ++i4) {
            float4 xv = *(const float4*)&xs[row_l * 132 + i4 * 4];
            float4 wv = *(const float4*)&wgs[e * 132 + i4 * 4];
            a0 += (double)xv.x * (double)wv.x;
            a1 += (double)xv.y * (double)wv.y;
            a2 += (double)xv.z * (double)wv.z;
            a3 += (double)xv.w * (double)wv.w;
        }
        __syncthreads();
    }
    double acc = (a0 + a1) + (a2 + a3);

    // argmax across the 16-lane expert group (first-max wins like np.argmax)
    double best = acc; int bi = e;
    #pragma unroll
    for (int off = 8; off >= 1; off >>= 1) {
        double ov = __shfl_xor(best, off);
        int    oi = __shfl_xor(bi, off);
        if (ov > best || (ov == best && oi < bi)) { best = ov; bi = oi; }
    }
    if (e == 0) {
        int pos = atomicAdd(&cnt[bi], 1);
        bucket[bi * NB + pos] = R0 + row_l;
    }
}

// ---------------- K2: We fp32 [E][K][N] -> bf16 transposed [E][N][K] ----------------
__global__ __launch_bounds__(256) void k_wet(const float* __restrict__ We,
                                             u16* __restrict__ WeT) {
    __shared__ u16 t[64 * 68];  // [n][k] pad 68
    const int e = blockIdx.z;
    const int n0 = blockIdx.y * 64;
    const int k0 = blockIdx.x * 64;
    const int tid = threadIdx.x;
    const float* src = We + (size_t)e * DK * DN;
    const int kl = tid >> 4;
    const int n4 = (tid & 15) * 4;
    #pragma unroll
    for (int r = 0; r < 4; ++r) {
        int k = kl + r * 16;
        float4 v = *(const float4*)&src[(size_t)(k0 + k) * DN + n0 + n4];
        t[(n4 + 0) * 68 + k] = f2bf(v.x);
        t[(n4 + 1) * 68 + k] = f2bf(v.y);
        t[(n4 + 2) * 68 + k] = f2bf(v.z);
        t[(n4 + 3) * 68 + k] = f2bf(v.w);
    }
    __syncthreads();
    u16* dst = WeT + (size_t)e * DN * DK;
    #pragma unroll
    for (int r = 0; r < 4; ++r) {
        int c = r * 256 + tid;
        int nl = c >> 4;
        int kq = (c & 15) * 4;
        *(u16x4*)&dst[(size_t)(n0 + nl) * DK + k0 + kq] = *(const u16x4*)&t[nl * 68 + kq];
    }
}

// ---------------- K2b: build compact (expert, row-tile) list ----------------
__global__ void k_tiles(const int* __restrict__ cnt, int* __restrict__ list,
                        int* __restrict__ total) {
    if (threadIdx.x == 0) {
        int t = 0;
        for (int e = 0; e < NE; ++e) {
            int n = (cnt[e] + TM - 1) / TM;
            for (int i = 0; i < n; ++i) list[t++] = (e << 16) | i;
        }
        *total = t;
    }
}

// ---------------- K3: grouped GEMM, bf16 MFMA 16x16x32, 128x128 tile ----------------
__global__ __launch_bounds__(256) void k_moe(const u16* __restrict__ xb,
                                             const u16* __restrict__ WeT,
                                             const float* __restrict__ be,
                                             const int* __restrict__ bucket,
                                             const int* __restrict__ cnt,
                                             const int* __restrict__ list,
                                             const int* __restrict__ total,
                                             float* __restrict__ out) {
    const int slot = blockIdx.x >> 3;
    const int nt = blockIdx.x & 7;
    if (slot >= *total) return;
    const int ent = list[slot];
    const int e = ent >> 16;
    const int mt = ent & 0xffff;
    const int cntE = cnt[e];
    const int m0 = mt * TM;
    const int n0 = nt * TN;

    __shared__ u16 aLds[TM * BK];  // 16 KB, xor-swizzled k-slots
    __shared__ u16 bLds[TN * BK];  // 16 KB

    const int tid = threadIdx.x;
    const int lane = tid & 63;
    const int w = tid >> 6;
    const int wr = w >> 1, wc = w & 1;
    const int lr = lane & 15, q = lane >> 4;

    // staging addresses: chunk c -> (row = c/8, stored slot = c%8, global k8 = slot ^ (row&7))
    long aoff[4]; long boff[4]; int ldsb[4];
    #pragma unroll
    for (int r = 0; r < 4; ++r) {
        int c = r * 256 + tid;
        int row = c >> 3;
        int k8 = (c & 7) ^ (row & 7);
        int m_idx = m0 + row; if (m_idx >= cntE) m_idx = cntE - 1;
        long rid = bucket[e * NB + m_idx];
        aoff[r] = rid * DK + k8 * 8;
        boff[r] = (long)e * DN * DK + (long)(n0 + row) * DK + k8 * 8;
        ldsb[r] = (r * 256 + (tid & ~63)) * 8;  // ushort elements (16B per chunk)
    }

    floatx4 acc[4][4];
    #pragma unroll
    for (int mi = 0; mi < 4; ++mi)
        #pragma unroll
        for (int ni = 0; ni < 4; ++ni)
            acc[mi][ni] = (floatx4)0.0f;

    for (int kk = 0; kk < DK; kk += BK) {
        #pragma unroll
        for (int r = 0; r < 4; ++r) {
            gld16(xb + aoff[r] + kk, &aLds[ldsb[r]]);
            gld16(WeT + boff[r] + kk, &bLds[ldsb[r]]);
        }
        __syncthreads();
        #pragma unroll
        for (int ks = 0; ks < 2; ++ks) {
            short8 af[4], bfr[4];
            const int slot_k = ((ks << 2) + q) ^ (lr & 7);
            #pragma unroll
            for (int mi = 0; mi < 4; ++mi) {
                int row = wr * 64 + mi * 16 + lr;
                af[mi] = *(const short8*)&aLds[row * BK + slot_k * 8];
                int nrow = wc * 64 + mi * 16 + lr;
                bfr[mi] = *(const short8*)&bLds[nrow * BK + slot_k * 8];
            }
            #pragma unroll
            for (int mi = 0; mi < 4; ++mi)
                #pragma unroll
                for (int ni = 0; ni < 4; ++ni)
                    acc[mi][ni] = __builtin_amdgcn_mfma_f32_16x16x32_bf16(
                        af[mi], bfr[ni], acc[mi][ni], 0, 0, 0);
        }
        __syncthreads();
    }

    // epilogue: C/D layout col = lane&15, row = q*4 + reg
    float bias[4];
    #pragma unroll
    for (int ni = 0; ni < 4; ++ni)
        bias[ni] = be[e * DN + n0 + wc * 64 + ni * 16 + lr];

    #pragma unroll
    for (int mi = 0; mi < 4; ++mi) {
        #pragma unroll
        for (int rr = 0; rr < 4; ++rr) {
            int row_l = wr * 64 + mi * 16 + q * 4 + rr;
            int m_idx = m0 + row_l;
            if (m_idx < cntE) {
                long rid = bucket[e * NB + m_idx];
                float* orow = out + rid * DN + n0 + wc * 64 + lr;
                #pragma unroll
                for (int ni = 0; ni < 4; ++ni)
                    orow[ni * 16] = acc[mi][ni][rr] + bias[ni];
            }
        }
    }
}

extern "C" void kernel_launch(void* const* d_in, const int* in_sizes, int n_in,
                              void* d_out, int out_size, void* d_ws, size_t ws_size,
                              hipStream_t stream) {
    const float* x  = (const float*)d_in[0];
    const float* Wg = (const float*)d_in[1];
    const float* bg = (const float*)d_in[2];
    const float* We = (const float*)d_in[3];
    const float* be = (const float*)d_in[4];
    float* out = (float*)d_out;

    int* cnt    = (int*)d_ws;           // 16 ints
    int* total  = cnt + 16;             // 1 int
    int* tlist  = cnt + 32;             // 80 ints
    int* bucket = cnt + 128;            // 16*8192 ints
    u16* xb  = (u16*)((char*)d_ws + (1u << 20));    // 16 MB @ 1MB
    u16* wet = (u16*)((char*)d_ws + (18u << 20));   // 32 MB @ 18MB

    k_init<<<1, 64, 0, stream>>>(cnt);
    k_gate<<<NB / 16, 256, 0, stream>>>(x, Wg, bg, xb, cnt, bucket);
    k_wet<<<dim3(16, 16, 16), 256, 0, stream>>>(We, wet);
    k_tiles<<<1, 64, 0, stream>>>(cnt, tlist, total);
    k_moe<<<MAX_TILES * 8, 256, 0, stream>>>(xb, wet, be, bucket, cnt, tlist, total, out);
}